// Round 4
// baseline (329.863 us; speedup 1.0000x reference)
//
#include <hip/hip_runtime.h>
#include <hip/hip_bf16.h>

// Problem: B=16384, H=2048
//   bdnf = sigmoid(x @ W^T + b)
//   xs   = x * pm
//   fi   = xs * (xs @ M^T) * (0.5/H)
//   out  = xs + bdnf * fi
// Identity: xs @ M^T = x @ (M * pm[col])^T  -> both GEMMs share A = bf16(x).
//
// R4: switch MFMA shape to 32x32x16 (µbench 2382-2495 TF vs 2075 for 16x16;
// half the MFMA instruction count). Schedule identical to R3: BM=256 BN=128
// BK=64, 8 waves (4Mx2N), 4 phases/K-tile, counted vmcnt(8)/vmcnt(2),
// T2 XOR swizzle, raw s_barrier, setprio around MFMA clusters.
// Per phase: 8 MFMA (2m x 2n x 2ks). A frags register-resident across tile.

#define M_DIM 16384
#define H_DIM 2048
#define BM 256
#define BN 128
#define BK 64
#define NTHREADS 512

typedef __attribute__((ext_vector_type(8))) short short8;
typedef __attribute__((ext_vector_type(16))) float floatx16;

#define GPTR(p) ((const __attribute__((address_space(1))) void*)(p))
#define LPTR(p) ((__attribute__((address_space(3))) void*)(p))

__device__ __forceinline__ unsigned short f2bf(float f) {
    __hip_bfloat16 h = __float2bfloat16(f);
    return *reinterpret_cast<unsigned short*>(&h);
}

// ---- pre-pass 1: xbf = bf16(x) -------------------------------------------
__global__ void cvt_x_kernel(const float* __restrict__ x,
                             unsigned short* __restrict__ xbf, long n) {
    long stride = (long)gridDim.x * blockDim.x * 4;
    for (long j = ((long)blockIdx.x * blockDim.x + threadIdx.x) * 4; j < n; j += stride) {
        float4 v = *reinterpret_cast<const float4*>(x + j);
        ushort4 o;
        o.x = f2bf(v.x); o.y = f2bf(v.y); o.z = f2bf(v.z); o.w = f2bf(v.w);
        *reinterpret_cast<ushort4*>(xbf + j) = o;
    }
}

// ---- pre-pass 2: Wbf = bf16(W); Mbf[j,k] = bf16(M[j,k]*pm[k]) ------------
__global__ void cvt_wm_kernel(const float* __restrict__ W,
                              const float* __restrict__ Mk,
                              const float* __restrict__ pm,
                              unsigned short* __restrict__ Wbf,
                              unsigned short* __restrict__ Mbf, long n) {
    long stride = (long)gridDim.x * blockDim.x * 4;
    for (long j = ((long)blockIdx.x * blockDim.x + threadIdx.x) * 4; j < n; j += stride) {
        float4 w = *reinterpret_cast<const float4*>(W + j);
        float4 m = *reinterpret_cast<const float4*>(Mk + j);
        float4 p = *reinterpret_cast<const float4*>(pm + (j & (H_DIM - 1)));
        ushort4 ow, om;
        ow.x = f2bf(w.x); ow.y = f2bf(w.y); ow.z = f2bf(w.z); ow.w = f2bf(w.w);
        om.x = f2bf(m.x * p.x); om.y = f2bf(m.y * p.y);
        om.z = f2bf(m.z * p.z); om.w = f2bf(m.w * p.w);
        *reinterpret_cast<ushort4*>(Wbf + j) = ow;
        *reinterpret_cast<ushort4*>(Mbf + j) = om;
    }
}

// swizzled ds_read: fragment at (row, ko) of a [rows][BK] bf16 tile.
__device__ __forceinline__ short8 lds_frag(const unsigned short* s, int row, int ko) {
    const int sw = (((ko >> 3) ^ (row & 7)) << 3);
    return *reinterpret_cast<const short8*>(&s[row * BK + sw]);
}

#define GLDS(src, dst) __builtin_amdgcn_global_load_lds(GPTR(src), LPTR(dst), 16, 0, 0)

#define STAGE_A(b, kt) do { \
    GLDS(gA0 + (kt),                      &sA[b][(srow      ) * BK + scol_l]); \
    GLDS(gA0 + (kt) + (size_t)64 *H_DIM,  &sA[b][(srow +  64) * BK + scol_l]); \
    GLDS(gA0 + (kt) + (size_t)128*H_DIM,  &sA[b][(srow + 128) * BK + scol_l]); \
    GLDS(gA0 + (kt) + (size_t)192*H_DIM,  &sA[b][(srow + 192) * BK + scol_l]); } while (0)

#define STAGE_W(b, kt) do { \
    GLDS(gW0 + (kt),                      &sW[b][(srow     ) * BK + scol_l]); \
    GLDS(gW0 + (kt) + (size_t)64 *H_DIM,  &sW[b][(srow + 64) * BK + scol_l]); } while (0)

#define STAGE_M(b, kt) do { \
    GLDS(gM0 + (kt),                      &sM[b][(srow     ) * BK + scol_l]); \
    GLDS(gM0 + (kt) + (size_t)64 *H_DIM,  &sM[b][(srow + 64) * BK + scol_l]); } while (0)

#define BAR() __builtin_amdgcn_s_barrier()
#define LGK0() do { asm volatile("s_waitcnt lgkmcnt(0)" ::: "memory"); \
                    __builtin_amdgcn_sched_barrier(0); } while (0)

#define MFMA32(a, b, c) __builtin_amdgcn_mfma_f32_32x32x16_bf16(a, b, c, 0, 0, 0)

// ph0: A ks0,ks1 + W ks0,ks1 -> acc1 ; stage next-tile A
#define PH0(ct, nt_, ktn) do { \
    _Pragma("unroll") for (int s = 0; s < 2; ++s) \
    _Pragma("unroll") for (int k2 = 0; k2 < 2; ++k2) \
        aA0[s*2+k2] = lds_frag(sA[ct], arow + s * 32, k2 * 16 + lh8); \
    _Pragma("unroll") for (int nn = 0; nn < 2; ++nn) \
    _Pragma("unroll") for (int k2 = 0; k2 < 2; ++k2) \
        bB[nn*2+k2] = lds_frag(sW[ct], brw + nn * 32, k2 * 16 + lh8); \
    STAGE_A(nt_, ktn); \
    BAR(); LGK0(); \
    __builtin_amdgcn_s_setprio(1); \
    _Pragma("unroll") for (int k2 = 0; k2 < 2; ++k2) \
    _Pragma("unroll") for (int s = 0; s < 2; ++s) \
    _Pragma("unroll") for (int nn = 0; nn < 2; ++nn) \
        acc1[s][nn] = MFMA32(aA0[s*2+k2], bB[nn*2+k2], acc1[s][nn]); \
    __builtin_amdgcn_s_setprio(0); \
    BAR(); } while (0)

// ph1: A ks2,ks3 + W ks2,ks3 -> acc1 ; stage next-tile W,M ; vmcnt(8)
#define PH1(ct, nt_, ktn) do { \
    _Pragma("unroll") for (int s = 0; s < 2; ++s) \
    _Pragma("unroll") for (int k2 = 0; k2 < 2; ++k2) \
        aA1[s*2+k2] = lds_frag(sA[ct], arow + s * 32, 32 + k2 * 16 + lh8); \
    _Pragma("unroll") for (int nn = 0; nn < 2; ++nn) \
    _Pragma("unroll") for (int k2 = 0; k2 < 2; ++k2) \
        bB[nn*2+k2] = lds_frag(sW[ct], brw + nn * 32, 32 + k2 * 16 + lh8); \
    STAGE_W(nt_, ktn); STAGE_M(nt_, ktn); \
    BAR(); LGK0(); \
    __builtin_amdgcn_s_setprio(1); \
    _Pragma("unroll") for (int k2 = 0; k2 < 2; ++k2) \
    _Pragma("unroll") for (int s = 0; s < 2; ++s) \
    _Pragma("unroll") for (int nn = 0; nn < 2; ++nn) \
        acc1[s][nn] = MFMA32(aA1[s*2+k2], bB[nn*2+k2], acc1[s][nn]); \
    __builtin_amdgcn_s_setprio(0); \
    asm volatile("s_waitcnt vmcnt(8)" ::: "memory"); \
    BAR(); } while (0)

// ph2: M ks0,ks1 -> acc2 (A from regs aA0)
#define PH2(ct) do { \
    _Pragma("unroll") for (int nn = 0; nn < 2; ++nn) \
    _Pragma("unroll") for (int k2 = 0; k2 < 2; ++k2) \
        bB[nn*2+k2] = lds_frag(sM[ct], brw + nn * 32, k2 * 16 + lh8); \
    BAR(); LGK0(); \
    __builtin_amdgcn_s_setprio(1); \
    _Pragma("unroll") for (int k2 = 0; k2 < 2; ++k2) \
    _Pragma("unroll") for (int s = 0; s < 2; ++s) \
    _Pragma("unroll") for (int nn = 0; nn < 2; ++nn) \
        acc2[s][nn] = MFMA32(aA0[s*2+k2], bB[nn*2+k2], acc2[s][nn]); \
    __builtin_amdgcn_s_setprio(0); \
    BAR(); } while (0)

// ph3: M ks2,ks3 -> acc2 (A from regs aA1) ; vmcnt(2)
#define PH3(ct) do { \
    _Pragma("unroll") for (int nn = 0; nn < 2; ++nn) \
    _Pragma("unroll") for (int k2 = 0; k2 < 2; ++k2) \
        bB[nn*2+k2] = lds_frag(sM[ct], brw + nn * 32, 32 + k2 * 16 + lh8); \
    BAR(); LGK0(); \
    __builtin_amdgcn_s_setprio(1); \
    _Pragma("unroll") for (int k2 = 0; k2 < 2; ++k2) \
    _Pragma("unroll") for (int s = 0; s < 2; ++s) \
    _Pragma("unroll") for (int nn = 0; nn < 2; ++nn) \
        acc2[s][nn] = MFMA32(aA1[s*2+k2], bB[nn*2+k2], acc2[s][nn]); \
    __builtin_amdgcn_s_setprio(0); \
    asm volatile("s_waitcnt vmcnt(2)" ::: "memory"); \
    BAR(); } while (0)

// ---- fused dual-GEMM + epilogue ------------------------------------------
__global__ __launch_bounds__(NTHREADS, 2)
void fused_gemm_kernel(const unsigned short* __restrict__ xbf,
                       const unsigned short* __restrict__ Wbf,
                       const unsigned short* __restrict__ Mbf,
                       const float* __restrict__ x,
                       const float* __restrict__ bias,
                       const float* __restrict__ pm,
                       float* __restrict__ out) {
    __shared__ __align__(16) unsigned short sA[2][BM * BK];  // 2 x 32 KB
    __shared__ __align__(16) unsigned short sW[2][BN * BK];  // 2 x 16 KB
    __shared__ __align__(16) unsigned short sM[2][BN * BK];  // 2 x 16 KB

    const int t    = threadIdx.x;
    const int brow = blockIdx.y * BM;
    const int bcol = blockIdx.x * BN;

    const int srow   = t >> 3;
    const int chunk  = t & 7;
    const int scol_l = chunk * 8;
    const int scol_g = (chunk ^ (srow & 7)) * 8;

    const int w    = t >> 6;
    const int lane = t & 63;
    const int wr   = w >> 1;             // 0..3 : 64-row strip
    const int wc   = w & 1;              // 0..1 : 64-col strip
    const int l31  = lane & 31;
    const int lh8  = (lane >> 5) * 8;    // k offset within a 16-k sub
    const int arow = wr * 64 + l31;      // A-frag base row (+s*32)
    const int brw  = wc * 64 + l31;      // B-frag base row (+nn*32)

    floatx16 acc1[2][2], acc2[2][2];
#pragma unroll
    for (int s = 0; s < 2; ++s)
#pragma unroll
        for (int nn = 0; nn < 2; ++nn) {
            acc1[s][nn] = (floatx16){0.f,0.f,0.f,0.f,0.f,0.f,0.f,0.f,
                                     0.f,0.f,0.f,0.f,0.f,0.f,0.f,0.f};
            acc2[s][nn] = (floatx16){0.f,0.f,0.f,0.f,0.f,0.f,0.f,0.f,
                                     0.f,0.f,0.f,0.f,0.f,0.f,0.f,0.f};
        }

    const unsigned short* gA0 = xbf + (size_t)(brow + srow) * H_DIM + scol_g;
    const unsigned short* gW0 = Wbf + (size_t)(bcol + srow) * H_DIM + scol_g;
    const unsigned short* gM0 = Mbf + (size_t)(bcol + srow) * H_DIM + scol_g;

    // prologue: stage tile 0, wait A+W (M drained at first PH1's vmcnt(8))
    STAGE_A(0, 0); STAGE_W(0, 0); STAGE_M(0, 0);
    asm volatile("s_waitcnt vmcnt(2)" ::: "memory");
    BAR();

    short8 aA0[4], aA1[4], bB[4];

#pragma unroll 1
    for (int i = 0; i < H_DIM / (2 * BK); ++i) {
        const int kn0 = i * 2 * BK + BK;
        const int kn1 = (i * 2 * BK + 2 * BK) & (H_DIM - 1);
        PH0(0, 1, kn0); PH1(0, 1, kn0); PH2(0); PH3(0);
        PH0(1, 0, kn1); PH1(1, 0, kn1); PH2(1); PH3(1);
    }

    // epilogue: out = xs + sigmoid(S1+b) * xs * S2 * (0.5/H), xs = x*pm (fp32)
    // 32x32 C/D layout: col = lane&31, row = (reg&3) + 8*(reg>>2) + 4*(lane>>5)
    const float c = 0.5f / (float)H_DIM;
#pragma unroll
    for (int nn = 0; nn < 2; ++nn) {
        const int gcol = bcol + wc * 64 + nn * 32 + l31;
        const float bj  = bias[gcol];
        const float pmj = pm[gcol];
#pragma unroll
        for (int s = 0; s < 2; ++s) {
            floatx16 a1 = acc1[s][nn];
            floatx16 a2 = acc2[s][nn];
            const int rowbase = brow + wr * 64 + s * 32 + 4 * (lane >> 5);
#pragma unroll
            for (int r = 0; r < 16; ++r) {
                const int grow = rowbase + (r & 3) + 8 * (r >> 2);
                const size_t idx = (size_t)grow * H_DIM + gcol;
                const float xs  = x[idx] * pmj;
                const float s1  = a1[r] + bj;
                const float sig = 1.0f / (1.0f + __expf(-s1));
                out[idx] = xs + sig * (xs * a2[r] * c);
            }
        }
    }
}

extern "C" void kernel_launch(void* const* d_in, const int* in_sizes, int n_in,
                              void* d_out, int out_size, void* d_ws, size_t ws_size,
                              hipStream_t stream) {
    const float* x   = (const float*)d_in[0];
    const float* W   = (const float*)d_in[1];
    const float* b   = (const float*)d_in[2];
    const float* pm  = (const float*)d_in[3];
    const float* Mk  = (const float*)d_in[4];
    float* out = (float*)d_out;

    const long n_x = (long)M_DIM * H_DIM;      // 33.5M
    const long n_w = (long)H_DIM * H_DIM;      // 4.2M

    // workspace layout: xbf | Wbf | Mbf  -> ~84 MB total
    unsigned short* xbf = (unsigned short*)d_ws;
    unsigned short* Wbf = xbf + n_x;
    unsigned short* Mbf = Wbf + n_w;

    cvt_x_kernel<<<4096, 256, 0, stream>>>(x, xbf, n_x);
    cvt_wm_kernel<<<2048, 256, 0, stream>>>(W, Mk, pm, Wbf, Mbf, n_w);

    dim3 grid(H_DIM / BN, M_DIM / BM);   // (16, 64)
    fused_gemm_kernel<<<grid, NTHREADS, 0, stream>>>(xbf, Wbf, Mbf, x, b, pm, out);
}

// Round 5
// 304.180 us; speedup vs baseline: 1.0844x; 1.0844x over previous
//
#include <hip/hip_runtime.h>
#include <hip/hip_bf16.h>

// Problem: B=16384, H=2048
//   bdnf = sigmoid(x @ W^T + b)
//   xs   = x * pm
//   fi   = xs * (xs @ M^T) * (0.5/H)
//   out  = xs + bdnf * fi
// Identity: xs @ M^T = x @ (M * pm[col])^T  -> both GEMMs share A = bf16(x).
//
// R5: back to 16x16x32 (R4's 32x32 = 4-way LDS conflict, wash). New schedule:
// one-phase-ahead fragment prefetch — each phase = {BAR; lgkm0; 8 MFMA;
// [next-phase ds_reads + stage issues]; 8 MFMA; [counted vmcnt]} so the LDS
// pipe drains under the MFMA pipe. 1 barrier/phase (4/K-tile, was 8).
// vmcnt: ph0-end vmcnt(4) drains cur-M before ph1-mid M reads;
//        ph2-end vmcnt(2) drains next A+W before ph3-mid next-ph0 reads.

#define M_DIM 16384
#define H_DIM 2048
#define BM 256
#define BN 128
#define BK 64
#define NTHREADS 512

typedef __attribute__((ext_vector_type(8))) short short8;
typedef __attribute__((ext_vector_type(4))) float floatx4;

#define GPTR(p) ((const __attribute__((address_space(1))) void*)(p))
#define LPTR(p) ((__attribute__((address_space(3))) void*)(p))

__device__ __forceinline__ unsigned short f2bf(float f) {
    __hip_bfloat16 h = __float2bfloat16(f);
    return *reinterpret_cast<unsigned short*>(&h);
}

// ---- pre-pass 1: xbf = bf16(x) -------------------------------------------
__global__ void cvt_x_kernel(const float* __restrict__ x,
                             unsigned short* __restrict__ xbf, long n) {
    long stride = (long)gridDim.x * blockDim.x * 4;
    for (long j = ((long)blockIdx.x * blockDim.x + threadIdx.x) * 4; j < n; j += stride) {
        float4 v = *reinterpret_cast<const float4*>(x + j);
        ushort4 o;
        o.x = f2bf(v.x); o.y = f2bf(v.y); o.z = f2bf(v.z); o.w = f2bf(v.w);
        *reinterpret_cast<ushort4*>(xbf + j) = o;
    }
}

// ---- pre-pass 2: Wbf = bf16(W); Mbf[j,k] = bf16(M[j,k]*pm[k]) ------------
__global__ void cvt_wm_kernel(const float* __restrict__ W,
                              const float* __restrict__ Mk,
                              const float* __restrict__ pm,
                              unsigned short* __restrict__ Wbf,
                              unsigned short* __restrict__ Mbf, long n) {
    long stride = (long)gridDim.x * blockDim.x * 4;
    for (long j = ((long)blockIdx.x * blockDim.x + threadIdx.x) * 4; j < n; j += stride) {
        float4 w = *reinterpret_cast<const float4*>(W + j);
        float4 m = *reinterpret_cast<const float4*>(Mk + j);
        float4 p = *reinterpret_cast<const float4*>(pm + (j & (H_DIM - 1)));
        ushort4 ow, om;
        ow.x = f2bf(w.x); ow.y = f2bf(w.y); ow.z = f2bf(w.z); ow.w = f2bf(w.w);
        om.x = f2bf(m.x * p.x); om.y = f2bf(m.y * p.y);
        om.z = f2bf(m.z * p.z); om.w = f2bf(m.w * p.w);
        *reinterpret_cast<ushort4*>(Wbf + j) = ow;
        *reinterpret_cast<ushort4*>(Mbf + j) = om;
    }
}

// swizzled ds_read: fragment at (row, ko) of a [rows][BK] bf16 tile.
__device__ __forceinline__ short8 lds_frag(const unsigned short* s, int row, int ko) {
    const int sw = (ko & 32) + ((((ko >> 3) ^ row) & 7) << 3);
    return *reinterpret_cast<const short8*>(&s[row * BK + sw]);
}

#define GLDS(src, dst) __builtin_amdgcn_global_load_lds(GPTR(src), LPTR(dst), 16, 0, 0)

#define STAGE_A(b, kt) do { \
    GLDS(gA0 + (kt),                      &sA[b][(srow      ) * BK + scol_l]); \
    GLDS(gA0 + (kt) + (size_t)64 *H_DIM,  &sA[b][(srow +  64) * BK + scol_l]); \
    GLDS(gA0 + (kt) + (size_t)128*H_DIM,  &sA[b][(srow + 128) * BK + scol_l]); \
    GLDS(gA0 + (kt) + (size_t)192*H_DIM,  &sA[b][(srow + 192) * BK + scol_l]); } while (0)

#define STAGE_W(b, kt) do { \
    GLDS(gW0 + (kt),                      &sW[b][(srow     ) * BK + scol_l]); \
    GLDS(gW0 + (kt) + (size_t)64 *H_DIM,  &sW[b][(srow + 64) * BK + scol_l]); } while (0)

#define STAGE_M(b, kt) do { \
    GLDS(gM0 + (kt),                      &sM[b][(srow     ) * BK + scol_l]); \
    GLDS(gM0 + (kt) + (size_t)64 *H_DIM,  &sM[b][(srow + 64) * BK + scol_l]); } while (0)

#define BAR()  __builtin_amdgcn_s_barrier()
#define SBAR() __builtin_amdgcn_sched_barrier(0)
#define LGK0() do { asm volatile("s_waitcnt lgkmcnt(0)" ::: "memory"); SBAR(); } while (0)
#define VMC(n) asm volatile("s_waitcnt vmcnt(" #n ")" ::: "memory")

#define MFMA16(a, b, c) __builtin_amdgcn_mfma_f32_16x16x32_bf16(a, b, c, 0, 0, 0)

// read A frags (4) for k-sub ks from buffer buf
#define RD_A(dst, buf, ks) do { \
    _Pragma("unroll") for (int m_ = 0; m_ < 4; ++m_) \
        dst[m_] = lds_frag(sA[buf], arow + m_ * 16, (ks) * 32 + lk8); } while (0)
// read B frags (4) for k-sub ks from W/M buffer buf
#define RD_B(dst, sb, buf, ks) do { \
    _Pragma("unroll") for (int n_ = 0; n_ < 4; ++n_) \
        dst[n_] = lds_frag(sb[buf], brw + n_ * 16, (ks) * 32 + lk8); } while (0)

#define MM_HALF(acc, av, bv, mlo) do { \
    _Pragma("unroll") for (int m_ = 0; m_ < 2; ++m_) \
    _Pragma("unroll") for (int n_ = 0; n_ < 4; ++n_) \
        acc[mlo + m_][n_] = MFMA16(av[mlo + m_], bv[n_], acc[mlo + m_][n_]); } while (0)

// phase: consume (av,bv) into acc; mid-group issues next phase's reads/stages
#define PHASE(acc, av, bv, MID, TAIL) do { \
    BAR(); LGK0(); \
    __builtin_amdgcn_s_setprio(1); MM_HALF(acc, av, bv, 0); __builtin_amdgcn_s_setprio(0); \
    SBAR(); MID; SBAR(); \
    __builtin_amdgcn_s_setprio(1); MM_HALF(acc, av, bv, 2); __builtin_amdgcn_s_setprio(0); \
    TAIL; } while (0)

// one K-tile: ct=cur buf, nt=next buf, aC0/aC1 = cur A frag sets,
// aN0 = next tile's ks0 A set, kst = k offset staged for next tile
#define TILE(ct, nt, aC0, aC1, aN0, kst) do { \
    PHASE(acc1, aC0, bP, { RD_A(aC1, ct, 1); RD_B(bQ, sW, ct, 1); STAGE_A(nt, kst); }, { VMC(4); }); \
    PHASE(acc1, aC1, bQ, { RD_B(bP, sM, ct, 0); STAGE_W(nt, kst); STAGE_M(nt, kst); }, {}); \
    PHASE(acc2, aC0, bP, { RD_B(bQ, sM, ct, 1); }, { VMC(2); }); \
    PHASE(acc2, aC1, bQ, { RD_A(aN0, nt, 0); RD_B(bP, sW, nt, 0); }, {}); } while (0)

// ---- fused dual-GEMM + epilogue ------------------------------------------
__global__ __launch_bounds__(NTHREADS, 2)
void fused_gemm_kernel(const unsigned short* __restrict__ xbf,
                       const unsigned short* __restrict__ Wbf,
                       const unsigned short* __restrict__ Mbf,
                       const float* __restrict__ x,
                       const float* __restrict__ bias,
                       const float* __restrict__ pm,
                       float* __restrict__ out) {
    __shared__ __align__(16) unsigned short sA[2][BM * BK];  // 2 x 32 KB
    __shared__ __align__(16) unsigned short sW[2][BN * BK];  // 2 x 16 KB
    __shared__ __align__(16) unsigned short sM[2][BN * BK];  // 2 x 16 KB

    const int t    = threadIdx.x;
    const int brow = blockIdx.y * BM;
    const int bcol = blockIdx.x * BN;

    const int srow   = t >> 3;
    const int chunk  = t & 7;
    const int scol_l = chunk * 8;
    const int scol_g = (chunk ^ (srow & 7)) * 8;

    const int w    = t >> 6;
    const int lane = t & 63;
    const int wr   = w >> 1;             // 0..3 : 64-row strip
    const int wc   = w & 1;              // 0..1 : 64-col strip
    const int lrow = lane & 15;
    const int lk8  = (lane >> 4) * 8;
    const int arow = wr * 64 + lrow;     // A-frag base row (+m*16)
    const int brw  = wc * 64 + lrow;     // B-frag base row (+n*16)

    floatx4 acc1[4][4], acc2[4][4];
#pragma unroll
    for (int m = 0; m < 4; ++m)
#pragma unroll
        for (int n = 0; n < 4; ++n) {
            acc1[m][n] = (floatx4){0.f, 0.f, 0.f, 0.f};
            acc2[m][n] = (floatx4){0.f, 0.f, 0.f, 0.f};
        }

    const unsigned short* gA0 = xbf + (size_t)(brow + srow) * H_DIM + scol_g;
    const unsigned short* gW0 = Wbf + (size_t)(bcol + srow) * H_DIM + scol_g;
    const unsigned short* gM0 = Mbf + (size_t)(bcol + srow) * H_DIM + scol_g;

    short8 aX0[4], aX1[4], aY0[4], aY1[4], bP[4], bQ[4];

    // prologue: stage tile 0 (A:4, W:2, M:2 ops); drain A+W; preload ph0 frags
    STAGE_A(0, 0); STAGE_W(0, 0); STAGE_M(0, 0);
    VMC(2);
    BAR();
    RD_A(aX0, 0, 0); RD_B(bP, sW, 0, 0);

#pragma unroll 1
    for (int i = 0; i < H_DIM / (2 * BK); ++i) {
        const int k1 = i * 2 * BK + BK;                      // stage for odd tile
        const int k2 = (i * 2 * BK + 2 * BK) & (H_DIM - 1);  // stage for next even
        TILE(0, 1, aX0, aX1, aY0, k1);
        TILE(1, 0, aY0, aY1, aX0, k2);
    }

    // epilogue: out = xs + sigmoid(S1+b) * xs * S2 * (0.5/H), xs = x*pm (fp32)
    const float c = 0.5f / (float)H_DIM;
#pragma unroll
    for (int n = 0; n < 4; ++n) {
        const int gcol = bcol + wc * 64 + n * 16 + lrow;
        const float bj  = bias[gcol];
        const float pmj = pm[gcol];
#pragma unroll
        for (int m = 0; m < 4; ++m) {
            floatx4 a1 = acc1[m][n];
            floatx4 a2 = acc2[m][n];
            const int growb = brow + wr * 64 + m * 16 + (lane >> 4) * 4;
#pragma unroll
            for (int r = 0; r < 4; ++r) {
                const size_t idx = (size_t)(growb + r) * H_DIM + gcol;
                const float xs  = x[idx] * pmj;
                const float s1  = a1[r] + bj;
                const float sig = 1.0f / (1.0f + __expf(-s1));
                out[idx] = xs + sig * (xs * a2[r] * c);
            }
        }
    }
}

extern "C" void kernel_launch(void* const* d_in, const int* in_sizes, int n_in,
                              void* d_out, int out_size, void* d_ws, size_t ws_size,
                              hipStream_t stream) {
    const float* x   = (const float*)d_in[0];
    const float* W   = (const float*)d_in[1];
    const float* b   = (const float*)d_in[2];
    const float* pm  = (const float*)d_in[3];
    const float* Mk  = (const float*)d_in[4];
    float* out = (float*)d_out;

    const long n_x = (long)M_DIM * H_DIM;      // 33.5M
    const long n_w = (long)H_DIM * H_DIM;      // 4.2M

    // workspace layout: xbf | Wbf | Mbf  -> ~84 MB total
    unsigned short* xbf = (unsigned short*)d_ws;
    unsigned short* Wbf = xbf + n_x;
    unsigned short* Mbf = Wbf + n_w;

    cvt_x_kernel<<<4096, 256, 0, stream>>>(x, xbf, n_x);
    cvt_wm_kernel<<<2048, 256, 0, stream>>>(W, Mk, pm, Wbf, Mbf, n_w);

    dim3 grid(H_DIM / BN, M_DIM / BM);   // (16, 64)
    fused_gemm_kernel<<<grid, NTHREADS, 0, stream>>>(xbf, Wbf, Mbf, x, b, pm, out);
}

// Round 6
// 293.312 us; speedup vs baseline: 1.1246x; 1.0371x over previous
//
#include <hip/hip_runtime.h>
#include <hip/hip_bf16.h>

// Problem: B=16384, H=2048
//   bdnf = sigmoid(x @ W^T + b)
//   xs   = x * pm
//   fi   = xs * (xs @ M^T) * (0.5/H)
//   out  = xs + bdnf * fi
// Identity: xs @ M^T = x @ (M * pm[col])^T  -> both GEMMs share A = bf16(x).
//
// R6: phase-START fragment reads (was mid-split). Each phase:
//   {BAR; lgkm0; [next-phase ds_reads + stage issues]; 16 MFMA; counted vmcnt}
// so the LDS pipe drains the next phase's reads under the FULL MFMA window
// (read content ~576 cyc < MFMA ~621 cyc). vmcnt ledger unchanged from R5:
// ph0-tail vmcnt(4) (drain cur M), ph2-tail vmcnt(2) (drain next A+W).
// Epilogue now reads xbf (bf16) instead of fp32 x: halves epilogue fetch.

#define M_DIM 16384
#define H_DIM 2048
#define BM 256
#define BN 128
#define BK 64
#define NTHREADS 512

typedef __attribute__((ext_vector_type(8))) short short8;
typedef __attribute__((ext_vector_type(4))) float floatx4;

#define GPTR(p) ((const __attribute__((address_space(1))) void*)(p))
#define LPTR(p) ((__attribute__((address_space(3))) void*)(p))

__device__ __forceinline__ unsigned short f2bf(float f) {
    __hip_bfloat16 h = __float2bfloat16(f);
    return *reinterpret_cast<unsigned short*>(&h);
}
__device__ __forceinline__ float bf2f(unsigned short u) {
    unsigned int v = ((unsigned int)u) << 16;
    return __builtin_bit_cast(float, v);
}

// ---- pre-pass 1: xbf = bf16(x) -------------------------------------------
__global__ void cvt_x_kernel(const float* __restrict__ x,
                             unsigned short* __restrict__ xbf, long n) {
    long stride = (long)gridDim.x * blockDim.x * 4;
    for (long j = ((long)blockIdx.x * blockDim.x + threadIdx.x) * 4; j < n; j += stride) {
        float4 v = *reinterpret_cast<const float4*>(x + j);
        ushort4 o;
        o.x = f2bf(v.x); o.y = f2bf(v.y); o.z = f2bf(v.z); o.w = f2bf(v.w);
        *reinterpret_cast<ushort4*>(xbf + j) = o;
    }
}

// ---- pre-pass 2: Wbf = bf16(W); Mbf[j,k] = bf16(M[j,k]*pm[k]) ------------
__global__ void cvt_wm_kernel(const float* __restrict__ W,
                              const float* __restrict__ Mk,
                              const float* __restrict__ pm,
                              unsigned short* __restrict__ Wbf,
                              unsigned short* __restrict__ Mbf, long n) {
    long stride = (long)gridDim.x * blockDim.x * 4;
    for (long j = ((long)blockIdx.x * blockDim.x + threadIdx.x) * 4; j < n; j += stride) {
        float4 w = *reinterpret_cast<const float4*>(W + j);
        float4 m = *reinterpret_cast<const float4*>(Mk + j);
        float4 p = *reinterpret_cast<const float4*>(pm + (j & (H_DIM - 1)));
        ushort4 ow, om;
        ow.x = f2bf(w.x); ow.y = f2bf(w.y); ow.z = f2bf(w.z); ow.w = f2bf(w.w);
        om.x = f2bf(m.x * p.x); om.y = f2bf(m.y * p.y);
        om.z = f2bf(m.z * p.z); om.w = f2bf(m.w * p.w);
        *reinterpret_cast<ushort4*>(Wbf + j) = ow;
        *reinterpret_cast<ushort4*>(Mbf + j) = om;
    }
}

// swizzled ds_read: fragment at (row, ko) of a [rows][BK] bf16 tile.
__device__ __forceinline__ short8 lds_frag(const unsigned short* s, int row, int ko) {
    const int sw = (ko & 32) + ((((ko >> 3) ^ row) & 7) << 3);
    return *reinterpret_cast<const short8*>(&s[row * BK + sw]);
}

#define GLDS(src, dst) __builtin_amdgcn_global_load_lds(GPTR(src), LPTR(dst), 16, 0, 0)

#define STAGE_A(b, kt) do { \
    GLDS(gA0 + (kt),                      &sA[b][(srow      ) * BK + scol_l]); \
    GLDS(gA0 + (kt) + (size_t)64 *H_DIM,  &sA[b][(srow +  64) * BK + scol_l]); \
    GLDS(gA0 + (kt) + (size_t)128*H_DIM,  &sA[b][(srow + 128) * BK + scol_l]); \
    GLDS(gA0 + (kt) + (size_t)192*H_DIM,  &sA[b][(srow + 192) * BK + scol_l]); } while (0)

#define STAGE_W(b, kt) do { \
    GLDS(gW0 + (kt),                      &sW[b][(srow     ) * BK + scol_l]); \
    GLDS(gW0 + (kt) + (size_t)64 *H_DIM,  &sW[b][(srow + 64) * BK + scol_l]); } while (0)

#define STAGE_M(b, kt) do { \
    GLDS(gM0 + (kt),                      &sM[b][(srow     ) * BK + scol_l]); \
    GLDS(gM0 + (kt) + (size_t)64 *H_DIM,  &sM[b][(srow + 64) * BK + scol_l]); } while (0)

#define BAR()  __builtin_amdgcn_s_barrier()
#define SBAR() __builtin_amdgcn_sched_barrier(0)
#define LGK0() do { asm volatile("s_waitcnt lgkmcnt(0)" ::: "memory"); SBAR(); } while (0)
#define VMC(n) asm volatile("s_waitcnt vmcnt(" #n ")" ::: "memory")

#define MFMA16(a, b, c) __builtin_amdgcn_mfma_f32_16x16x32_bf16(a, b, c, 0, 0, 0)

// read A frags (4) for k-sub ks from buffer buf
#define RD_A(dst, buf, ks) do { \
    _Pragma("unroll") for (int m_ = 0; m_ < 4; ++m_) \
        dst[m_] = lds_frag(sA[buf], arow + m_ * 16, (ks) * 32 + lk8); } while (0)
// read B frags (4) for k-sub ks from W/M buffer buf
#define RD_B(dst, sb, buf, ks) do { \
    _Pragma("unroll") for (int n_ = 0; n_ < 4; ++n_) \
        dst[n_] = lds_frag(sb[buf], brw + n_ * 16, (ks) * 32 + lk8); } while (0)

#define MM_ALL(acc, av, bv) do { \
    _Pragma("unroll") for (int m_ = 0; m_ < 4; ++m_) \
    _Pragma("unroll") for (int n_ = 0; n_ < 4; ++n_) \
        acc[m_][n_] = MFMA16(av[m_], bv[n_], acc[m_][n_]); } while (0)

// phase: PRE (next-phase reads + stage issues) BEFORE the 16-MFMA cluster.
#define PHASE(acc, av, bv, PRE, TAIL) do { \
    BAR(); LGK0(); \
    PRE; SBAR(); \
    __builtin_amdgcn_s_setprio(1); MM_ALL(acc, av, bv); __builtin_amdgcn_s_setprio(0); \
    TAIL; } while (0)

// one K-tile: ct=cur buf, nt=next buf, aC0/aC1 = cur A frag sets,
// aN0 = next tile's ks0 A set, kst = k offset staged for next tile
#define TILE(ct, nt, aC0, aC1, aN0, kst) do { \
    PHASE(acc1, aC0, bP, { RD_A(aC1, ct, 1); RD_B(bQ, sW, ct, 1); STAGE_A(nt, kst); }, { VMC(4); }); \
    PHASE(acc1, aC1, bQ, { RD_B(bP, sM, ct, 0); STAGE_W(nt, kst); STAGE_M(nt, kst); }, {}); \
    PHASE(acc2, aC0, bP, { RD_B(bQ, sM, ct, 1); }, { VMC(2); }); \
    PHASE(acc2, aC1, bQ, { RD_A(aN0, nt, 0); RD_B(bP, sW, nt, 0); }, {}); } while (0)

// ---- fused dual-GEMM + epilogue ------------------------------------------
__global__ __launch_bounds__(NTHREADS, 2)
void fused_gemm_kernel(const unsigned short* __restrict__ xbf,
                       const unsigned short* __restrict__ Wbf,
                       const unsigned short* __restrict__ Mbf,
                       const float* __restrict__ bias,
                       const float* __restrict__ pm,
                       float* __restrict__ out) {
    __shared__ __align__(16) unsigned short sA[2][BM * BK];  // 2 x 32 KB
    __shared__ __align__(16) unsigned short sW[2][BN * BK];  // 2 x 16 KB
    __shared__ __align__(16) unsigned short sM[2][BN * BK];  // 2 x 16 KB

    const int t    = threadIdx.x;
    const int brow = blockIdx.y * BM;
    const int bcol = blockIdx.x * BN;

    const int srow   = t >> 3;
    const int chunk  = t & 7;
    const int scol_l = chunk * 8;
    const int scol_g = (chunk ^ (srow & 7)) * 8;

    const int w    = t >> 6;
    const int lane = t & 63;
    const int wr   = w >> 1;             // 0..3 : 64-row strip
    const int wc   = w & 1;              // 0..1 : 64-col strip
    const int lrow = lane & 15;
    const int lk8  = (lane >> 4) * 8;
    const int arow = wr * 64 + lrow;     // A-frag base row (+m*16)
    const int brw  = wc * 64 + lrow;     // B-frag base row (+n*16)

    floatx4 acc1[4][4], acc2[4][4];
#pragma unroll
    for (int m = 0; m < 4; ++m)
#pragma unroll
        for (int n = 0; n < 4; ++n) {
            acc1[m][n] = (floatx4){0.f, 0.f, 0.f, 0.f};
            acc2[m][n] = (floatx4){0.f, 0.f, 0.f, 0.f};
        }

    const unsigned short* gA0 = xbf + (size_t)(brow + srow) * H_DIM + scol_g;
    const unsigned short* gW0 = Wbf + (size_t)(bcol + srow) * H_DIM + scol_g;
    const unsigned short* gM0 = Mbf + (size_t)(bcol + srow) * H_DIM + scol_g;

    short8 aX0[4], aX1[4], aY0[4], aY1[4], bP[4], bQ[4];

    // prologue: stage tile 0; drain A+W (M drains at tile0.ph0 tail); preload
    STAGE_A(0, 0); STAGE_W(0, 0); STAGE_M(0, 0);
    VMC(2);
    BAR();
    RD_A(aX0, 0, 0); RD_B(bP, sW, 0, 0);

#pragma unroll 1
    for (int i = 0; i < H_DIM / (2 * BK); ++i) {
        const int k1 = i * 2 * BK + BK;                      // stage for odd tile
        const int k2 = (i * 2 * BK + 2 * BK) & (H_DIM - 1);  // stage for next even
        TILE(0, 1, aX0, aX1, aY0, k1);
        TILE(1, 0, aY0, aY1, aX0, k2);
    }

    // epilogue: out = xs + sigmoid(S1+b) * xs * S2 * (0.5/H), xs = bf16(x)*pm
    const float c = 0.5f / (float)H_DIM;
#pragma unroll
    for (int n = 0; n < 4; ++n) {
        const int gcol = bcol + wc * 64 + n * 16 + lrow;
        const float bj  = bias[gcol];
        const float pmj = pm[gcol];
#pragma unroll
        for (int m = 0; m < 4; ++m) {
            floatx4 a1 = acc1[m][n];
            floatx4 a2 = acc2[m][n];
            const int growb = brow + wr * 64 + m * 16 + (lane >> 4) * 4;
#pragma unroll
            for (int r = 0; r < 4; ++r) {
                const size_t idx = (size_t)(growb + r) * H_DIM + gcol;
                const float xs  = bf2f(xbf[idx]) * pmj;
                const float s1  = a1[r] + bj;
                const float sig = 1.0f / (1.0f + __expf(-s1));
                out[idx] = xs + sig * (xs * a2[r] * c);
            }
        }
    }
}

extern "C" void kernel_launch(void* const* d_in, const int* in_sizes, int n_in,
                              void* d_out, int out_size, void* d_ws, size_t ws_size,
                              hipStream_t stream) {
    const float* x   = (const float*)d_in[0];
    const float* W   = (const float*)d_in[1];
    const float* b   = (const float*)d_in[2];
    const float* pm  = (const float*)d_in[3];
    const float* Mk  = (const float*)d_in[4];
    float* out = (float*)d_out;

    const long n_x = (long)M_DIM * H_DIM;      // 33.5M
    const long n_w = (long)H_DIM * H_DIM;      // 4.2M

    // workspace layout: xbf | Wbf | Mbf  -> ~84 MB total
    unsigned short* xbf = (unsigned short*)d_ws;
    unsigned short* Wbf = xbf + n_x;
    unsigned short* Mbf = Wbf + n_w;

    cvt_x_kernel<<<4096, 256, 0, stream>>>(x, xbf, n_x);
    cvt_wm_kernel<<<2048, 256, 0, stream>>>(W, Mk, pm, Wbf, Mbf, n_w);

    dim3 grid(H_DIM / BN, M_DIM / BM);   // (16, 64)
    fused_gemm_kernel<<<grid, NTHREADS, 0, stream>>>(xbf, Wbf, Mbf, b, pm, out);
}

// Round 7
// 288.096 us; speedup vs baseline: 1.1450x; 1.0181x over previous
//
#include <hip/hip_runtime.h>
#include <hip/hip_bf16.h>

// Problem: B=16384, H=2048
//   bdnf = sigmoid(x @ W^T + b)
//   xs   = x * pm
//   fi   = xs * (xs @ M^T) * (0.5/H)
//   out  = xs + bdnf * fi
// Identity: xs @ M^T = x @ (M * pm[col])^T  -> both GEMMs share A = bf16(x).
//
// R7: T19 sched_group_barrier interleave inside each phase: {MFMA 2, DS_READ 1,
// VMEM 1} repeating, so ds_read bursts don't block MFMA issue (R6 measured
// phase = MFMA + LDS serialized sum). Source order & vmcnt ledger unchanged:
// ph0-tail vmcnt(4) (drain cur M), ph2-tail vmcnt(2) (drain next A+W).

#define M_DIM 16384
#define H_DIM 2048
#define BM 256
#define BN 128
#define BK 64
#define NTHREADS 512

typedef __attribute__((ext_vector_type(8))) short short8;
typedef __attribute__((ext_vector_type(4))) float floatx4;

#define GPTR(p) ((const __attribute__((address_space(1))) void*)(p))
#define LPTR(p) ((__attribute__((address_space(3))) void*)(p))

__device__ __forceinline__ unsigned short f2bf(float f) {
    __hip_bfloat16 h = __float2bfloat16(f);
    return *reinterpret_cast<unsigned short*>(&h);
}
__device__ __forceinline__ float bf2f(unsigned short u) {
    unsigned int v = ((unsigned int)u) << 16;
    return __builtin_bit_cast(float, v);
}

// ---- pre-pass 1: xbf = bf16(x) -------------------------------------------
__global__ void cvt_x_kernel(const float* __restrict__ x,
                             unsigned short* __restrict__ xbf, long n) {
    long stride = (long)gridDim.x * blockDim.x * 4;
    for (long j = ((long)blockIdx.x * blockDim.x + threadIdx.x) * 4; j < n; j += stride) {
        float4 v = *reinterpret_cast<const float4*>(x + j);
        ushort4 o;
        o.x = f2bf(v.x); o.y = f2bf(v.y); o.z = f2bf(v.z); o.w = f2bf(v.w);
        *reinterpret_cast<ushort4*>(xbf + j) = o;
    }
}

// ---- pre-pass 2: Wbf = bf16(W); Mbf[j,k] = bf16(M[j,k]*pm[k]) ------------
__global__ void cvt_wm_kernel(const float* __restrict__ W,
                              const float* __restrict__ Mk,
                              const float* __restrict__ pm,
                              unsigned short* __restrict__ Wbf,
                              unsigned short* __restrict__ Mbf, long n) {
    long stride = (long)gridDim.x * blockDim.x * 4;
    for (long j = ((long)blockIdx.x * blockDim.x + threadIdx.x) * 4; j < n; j += stride) {
        float4 w = *reinterpret_cast<const float4*>(W + j);
        float4 m = *reinterpret_cast<const float4*>(Mk + j);
        float4 p = *reinterpret_cast<const float4*>(pm + (j & (H_DIM - 1)));
        ushort4 ow, om;
        ow.x = f2bf(w.x); ow.y = f2bf(w.y); ow.z = f2bf(w.z); ow.w = f2bf(w.w);
        om.x = f2bf(m.x * p.x); om.y = f2bf(m.y * p.y);
        om.z = f2bf(m.z * p.z); om.w = f2bf(m.w * p.w);
        *reinterpret_cast<ushort4*>(Wbf + j) = ow;
        *reinterpret_cast<ushort4*>(Mbf + j) = om;
    }
}

// swizzled ds_read: fragment at (row, ko) of a [rows][BK] bf16 tile.
__device__ __forceinline__ short8 lds_frag(const unsigned short* s, int row, int ko) {
    const int sw = (ko & 32) + ((((ko >> 3) ^ row) & 7) << 3);
    return *reinterpret_cast<const short8*>(&s[row * BK + sw]);
}

#define GLDS(src, dst) __builtin_amdgcn_global_load_lds(GPTR(src), LPTR(dst), 16, 0, 0)

#define STAGE_A(b, kt) do { \
    GLDS(gA0 + (kt),                      &sA[b][(srow      ) * BK + scol_l]); \
    GLDS(gA0 + (kt) + (size_t)64 *H_DIM,  &sA[b][(srow +  64) * BK + scol_l]); \
    GLDS(gA0 + (kt) + (size_t)128*H_DIM,  &sA[b][(srow + 128) * BK + scol_l]); \
    GLDS(gA0 + (kt) + (size_t)192*H_DIM,  &sA[b][(srow + 192) * BK + scol_l]); } while (0)

#define STAGE_W(b, kt) do { \
    GLDS(gW0 + (kt),                      &sW[b][(srow     ) * BK + scol_l]); \
    GLDS(gW0 + (kt) + (size_t)64 *H_DIM,  &sW[b][(srow + 64) * BK + scol_l]); } while (0)

#define STAGE_M(b, kt) do { \
    GLDS(gM0 + (kt),                      &sM[b][(srow     ) * BK + scol_l]); \
    GLDS(gM0 + (kt) + (size_t)64 *H_DIM,  &sM[b][(srow + 64) * BK + scol_l]); } while (0)

#define BAR()  __builtin_amdgcn_s_barrier()
#define SBAR() __builtin_amdgcn_sched_barrier(0)
#define LGK0() do { asm volatile("s_waitcnt lgkmcnt(0)" ::: "memory"); SBAR(); } while (0)
#define VMC(n) asm volatile("s_waitcnt vmcnt(" #n ")" ::: "memory")

#define MFMA16(a, b, c) __builtin_amdgcn_mfma_f32_16x16x32_bf16(a, b, c, 0, 0, 0)

// sched_group_barrier masks: MFMA=0x8, DS_READ=0x100, VMEM=0x10
#define SGB(mask, n) __builtin_amdgcn_sched_group_barrier(mask, n, 0)

// interleave pin patterns: 16 MFMA + R ds_reads + V vmem issues per phase
#define ILV_R8V4() do { \
    _Pragma("unroll") for (int i_ = 0; i_ < 4; ++i_) { SGB(0x8,2); SGB(0x100,1); SGB(0x10,1); } \
    _Pragma("unroll") for (int i_ = 0; i_ < 4; ++i_) { SGB(0x8,2); SGB(0x100,1); } } while (0)
#define ILV_R4V4() do { \
    _Pragma("unroll") for (int i_ = 0; i_ < 4; ++i_) { SGB(0x8,2); SGB(0x100,1); SGB(0x10,1); } \
    SGB(0x8,8); } while (0)
#define ILV_R4() do { \
    _Pragma("unroll") for (int i_ = 0; i_ < 4; ++i_) { SGB(0x8,2); SGB(0x100,1); } \
    SGB(0x8,8); } while (0)
#define ILV_R8() do { \
    _Pragma("unroll") for (int i_ = 0; i_ < 8; ++i_) { SGB(0x8,2); SGB(0x100,1); } } while (0)

// read A frags (4) for k-sub ks from buffer buf
#define RD_A(dst, buf, ks) do { \
    _Pragma("unroll") for (int m_ = 0; m_ < 4; ++m_) \
        dst[m_] = lds_frag(sA[buf], arow + m_ * 16, (ks) * 32 + lk8); } while (0)
// read B frags (4) for k-sub ks from W/M buffer buf
#define RD_B(dst, sb, buf, ks) do { \
    _Pragma("unroll") for (int n_ = 0; n_ < 4; ++n_) \
        dst[n_] = lds_frag(sb[buf], brw + n_ * 16, (ks) * 32 + lk8); } while (0)

#define MM_ALL(acc, av, bv) do { \
    _Pragma("unroll") for (int m_ = 0; m_ < 4; ++m_) \
    _Pragma("unroll") for (int n_ = 0; n_ < 4; ++n_) \
        acc[m_][n_] = MFMA16(av[m_], bv[n_], acc[m_][n_]); } while (0)

// phase: PRE (next-phase reads + stage issues) + 16 MFMA, interleaved by ILV.
#define PHASE(acc, av, bv, PRE, ILV, TAIL) do { \
    BAR(); LGK0(); \
    __builtin_amdgcn_s_setprio(1); \
    PRE; \
    MM_ALL(acc, av, bv); \
    ILV; \
    __builtin_amdgcn_s_setprio(0); \
    SBAR(); \
    TAIL; } while (0)

// one K-tile: ct=cur buf, nt=next buf, aC0/aC1 = cur A frag sets,
// aN0 = next tile's ks0 A set, kst = k offset staged for next tile
#define TILE(ct, nt, aC0, aC1, aN0, kst) do { \
    PHASE(acc1, aC0, bP, { RD_A(aC1, ct, 1); RD_B(bQ, sW, ct, 1); STAGE_A(nt, kst); }, ILV_R8V4(), { VMC(4); }); \
    PHASE(acc1, aC1, bQ, { RD_B(bP, sM, ct, 0); STAGE_W(nt, kst); STAGE_M(nt, kst); }, ILV_R4V4(), {}); \
    PHASE(acc2, aC0, bP, { RD_B(bQ, sM, ct, 1); }, ILV_R4(), { VMC(2); }); \
    PHASE(acc2, aC1, bQ, { RD_A(aN0, nt, 0); RD_B(bP, sW, nt, 0); }, ILV_R8(), {}); } while (0)

// ---- fused dual-GEMM + epilogue ------------------------------------------
__global__ __launch_bounds__(NTHREADS, 2)
void fused_gemm_kernel(const unsigned short* __restrict__ xbf,
                       const unsigned short* __restrict__ Wbf,
                       const unsigned short* __restrict__ Mbf,
                       const float* __restrict__ bias,
                       const float* __restrict__ pm,
                       float* __restrict__ out) {
    __shared__ __align__(16) unsigned short sA[2][BM * BK];  // 2 x 32 KB
    __shared__ __align__(16) unsigned short sW[2][BN * BK];  // 2 x 16 KB
    __shared__ __align__(16) unsigned short sM[2][BN * BK];  // 2 x 16 KB

    const int t    = threadIdx.x;
    const int brow = blockIdx.y * BM;
    const int bcol = blockIdx.x * BN;

    const int srow   = t >> 3;
    const int chunk  = t & 7;
    const int scol_l = chunk * 8;
    const int scol_g = (chunk ^ (srow & 7)) * 8;

    const int w    = t >> 6;
    const int lane = t & 63;
    const int wr   = w >> 1;             // 0..3 : 64-row strip
    const int wc   = w & 1;              // 0..1 : 64-col strip
    const int lrow = lane & 15;
    const int lk8  = (lane >> 4) * 8;
    const int arow = wr * 64 + lrow;     // A-frag base row (+m*16)
    const int brw  = wc * 64 + lrow;     // B-frag base row (+n*16)

    floatx4 acc1[4][4], acc2[4][4];
#pragma unroll
    for (int m = 0; m < 4; ++m)
#pragma unroll
        for (int n = 0; n < 4; ++n) {
            acc1[m][n] = (floatx4){0.f, 0.f, 0.f, 0.f};
            acc2[m][n] = (floatx4){0.f, 0.f, 0.f, 0.f};
        }

    const unsigned short* gA0 = xbf + (size_t)(brow + srow) * H_DIM + scol_g;
    const unsigned short* gW0 = Wbf + (size_t)(bcol + srow) * H_DIM + scol_g;
    const unsigned short* gM0 = Mbf + (size_t)(bcol + srow) * H_DIM + scol_g;

    short8 aX0[4], aX1[4], aY0[4], aY1[4], bP[4], bQ[4];

    // prologue: stage tile 0; drain A+W (M drains at tile0.ph0 tail); preload
    STAGE_A(0, 0); STAGE_W(0, 0); STAGE_M(0, 0);
    VMC(2);
    BAR();
    RD_A(aX0, 0, 0); RD_B(bP, sW, 0, 0);

#pragma unroll 1
    for (int i = 0; i < H_DIM / (2 * BK); ++i) {
        const int k1 = i * 2 * BK + BK;                      // stage for odd tile
        const int k2 = (i * 2 * BK + 2 * BK) & (H_DIM - 1);  // stage for next even
        TILE(0, 1, aX0, aX1, aY0, k1);
        TILE(1, 0, aY0, aY1, aX0, k2);
    }

    // epilogue: out = xs + sigmoid(S1+b) * xs * S2 * (0.5/H), xs = bf16(x)*pm
    const float c = 0.5f / (float)H_DIM;
#pragma unroll
    for (int n = 0; n < 4; ++n) {
        const int gcol = bcol + wc * 64 + n * 16 + lrow;
        const float bj  = bias[gcol];
        const float pmj = pm[gcol];
#pragma unroll
        for (int m = 0; m < 4; ++m) {
            floatx4 a1 = acc1[m][n];
            floatx4 a2 = acc2[m][n];
            const int growb = brow + wr * 64 + m * 16 + (lane >> 4) * 4;
#pragma unroll
            for (int r = 0; r < 4; ++r) {
                const size_t idx = (size_t)(growb + r) * H_DIM + gcol;
                const float xs  = bf2f(xbf[idx]) * pmj;
                const float s1  = a1[r] + bj;
                const float sig = 1.0f / (1.0f + __expf(-s1));
                out[idx] = xs + sig * (xs * a2[r] * c);
            }
        }
    }
}

extern "C" void kernel_launch(void* const* d_in, const int* in_sizes, int n_in,
                              void* d_out, int out_size, void* d_ws, size_t ws_size,
                              hipStream_t stream) {
    const float* x   = (const float*)d_in[0];
    const float* W   = (const float*)d_in[1];
    const float* b   = (const float*)d_in[2];
    const float* pm  = (const float*)d_in[3];
    const float* Mk  = (const float*)d_in[4];
    float* out = (float*)d_out;

    const long n_x = (long)M_DIM * H_DIM;      // 33.5M
    const long n_w = (long)H_DIM * H_DIM;      // 4.2M

    // workspace layout: xbf | Wbf | Mbf  -> ~84 MB total
    unsigned short* xbf = (unsigned short*)d_ws;
    unsigned short* Wbf = xbf + n_x;
    unsigned short* Mbf = Wbf + n_w;

    cvt_x_kernel<<<4096, 256, 0, stream>>>(x, xbf, n_x);
    cvt_wm_kernel<<<2048, 256, 0, stream>>>(W, Mk, pm, Wbf, Mbf, n_w);

    dim3 grid(H_DIM / BN, M_DIM / BM);   // (16, 64)
    fused_gemm_kernel<<<grid, NTHREADS, 0, stream>>>(xbf, Wbf, Mbf, b, pm, out);
}

// Round 8
// 209.091 us; speedup vs baseline: 1.5776x; 1.3779x over previous
//
#include <hip/hip_runtime.h>

// Problem: B=16384, H=2048
//   bdnf = sigmoid(x @ W^T + b)
//   xs   = x * pm
//   fi   = xs * (xs @ M^T) * (0.5/H)
//   out  = xs + bdnf * fi
// Identity: xs @ M^T = x @ (M * pm[col])^T  -> both GEMMs share A = fp8(x).
//
// R8: MX-scaled fp8 dual GEMM (mfma_scale_f32_16x16x128_f8f6f4, K=128).
//  - A = fp8(x), scale_a = 127 (1.0); B = fp8(16*W) / fp8(16*M*pm),
//    scale_b = 123 (2^-4) -> exact /16, avoids e4m3 subnormal range.
//  - GEMM error is structurally damped (sigmoid-bounded S1; S2 * 2.4e-4),
//    xs stays fp32-exact in the epilogue -> absmax budget safe.
//  - LDS rows 128 B (8 x 16B chunks), XOR swizzle chunk^=(row&7), staged
//    linearly by global_load_lds w=16 with pre-swizzled global source.
//    NOTE: fixed R5-R7's swizzle-read bug: correct form ((ko>>3)^(row&7)).
//  - 2 phases/K-tile: PH_W {rd A,W | stage all t+1 | 16 MFMA acc1 | vmcnt(8)}
//                     PH_M {rd M  |                 16 MFMA acc2 | vmcnt(2)}
//    drains: PH_M-tail vmcnt(2) releases A,W(t+1); PH_W-tail vmcnt(8)
//    releases M(t+1). Never 0 in-loop.

#define M_DIM 16384
#define H_DIM 2048
#define BM 256
#define BN 128
#define BKB 128            // K-tile in bytes = 128 fp8 elements
#define NKT (H_DIM / BKB)  // 16 K-tiles
#define NTHREADS 512

typedef __attribute__((ext_vector_type(4))) int   intx4;
typedef __attribute__((ext_vector_type(8))) int   intx8;
typedef __attribute__((ext_vector_type(4))) float floatx4;

#define GPTR(p) ((const __attribute__((address_space(1))) void*)(p))
#define LPTR(p) ((__attribute__((address_space(3))) void*)(p))

__device__ __forceinline__ int pk4(float a, float b, float c, float d) {
    int v = __builtin_amdgcn_cvt_pk_fp8_f32(a, b, 0, false);
    v     = __builtin_amdgcn_cvt_pk_fp8_f32(c, d, v, true);
    return v;
}

// ---- pre-pass 1: x8 = fp8(x) ---------------------------------------------
__global__ void cvt_x8_kernel(const float* __restrict__ x,
                              unsigned char* __restrict__ x8, long n) {
    long stride = (long)gridDim.x * blockDim.x * 8;
    for (long j = ((long)blockIdx.x * blockDim.x + threadIdx.x) * 8; j < n; j += stride) {
        float4 v0 = *reinterpret_cast<const float4*>(x + j);
        float4 v1 = *reinterpret_cast<const float4*>(x + j + 4);
        int2 o;
        o.x = pk4(v0.x, v0.y, v0.z, v0.w);
        o.y = pk4(v1.x, v1.y, v1.z, v1.w);
        *reinterpret_cast<int2*>(x8 + j) = o;
    }
}

// ---- pre-pass 2: W8 = fp8(16*W); M8 = fp8(16*M*pm[col]) ------------------
__global__ void cvt_wm8_kernel(const float* __restrict__ W,
                               const float* __restrict__ Mk,
                               const float* __restrict__ pm,
                               unsigned char* __restrict__ W8,
                               unsigned char* __restrict__ M8, long n) {
    long stride = (long)gridDim.x * blockDim.x * 8;
    for (long j = ((long)blockIdx.x * blockDim.x + threadIdx.x) * 8; j < n; j += stride) {
        float4 w0 = *reinterpret_cast<const float4*>(W + j);
        float4 w1 = *reinterpret_cast<const float4*>(W + j + 4);
        float4 m0 = *reinterpret_cast<const float4*>(Mk + j);
        float4 m1 = *reinterpret_cast<const float4*>(Mk + j + 4);
        const long col = j & (H_DIM - 1);
        float4 p0 = *reinterpret_cast<const float4*>(pm + col);
        float4 p1 = *reinterpret_cast<const float4*>(pm + col + 4);
        int2 ow, om;
        ow.x = pk4(w0.x * 16.f, w0.y * 16.f, w0.z * 16.f, w0.w * 16.f);
        ow.y = pk4(w1.x * 16.f, w1.y * 16.f, w1.z * 16.f, w1.w * 16.f);
        om.x = pk4(m0.x * p0.x * 16.f, m0.y * p0.y * 16.f,
                   m0.z * p0.z * 16.f, m0.w * p0.w * 16.f);
        om.y = pk4(m1.x * p1.x * 16.f, m1.y * p1.y * 16.f,
                   m1.z * p1.z * 16.f, m1.w * p1.w * 16.f);
        *reinterpret_cast<int2*>(W8 + j) = ow;
        *reinterpret_cast<int2*>(M8 + j) = om;
    }
}

// swizzled fp8 frag read: 32 bytes (k-block) for lane-group g of row `row`.
// LDS chunk c holds global chunk c^(row&7); want global chunks {2g, 2g+1}.
__device__ __forceinline__ intx8 frag8(const unsigned char* s, int row, int g) {
    const unsigned char* p = s + row * BKB;
    const int c0 = ((2 * g)     ^ (row & 7)) * 16;
    const int c1 = ((2 * g + 1) ^ (row & 7)) * 16;
    intx4 lo = *reinterpret_cast<const intx4*>(p + c0);
    intx4 hi = *reinterpret_cast<const intx4*>(p + c1);
    return (intx8){lo.x, lo.y, lo.z, lo.w, hi.x, hi.y, hi.z, hi.w};
}

#define GLDS(src, dst) __builtin_amdgcn_global_load_lds(GPTR(src), LPTR(dst), 16, 0, 0)

#define STAGE_A(b, kt) do { \
    GLDS(gA0 + (kt),                       &sA[b][(srow      ) * BKB + scol_l]); \
    GLDS(gA0 + (kt) + (size_t)64  * H_DIM, &sA[b][(srow +  64) * BKB + scol_l]); \
    GLDS(gA0 + (kt) + (size_t)128 * H_DIM, &sA[b][(srow + 128) * BKB + scol_l]); \
    GLDS(gA0 + (kt) + (size_t)192 * H_DIM, &sA[b][(srow + 192) * BKB + scol_l]); } while (0)

#define STAGE_W(b, kt) do { \
    GLDS(gW0 + (kt),                       &sW[b][(srow     ) * BKB + scol_l]); \
    GLDS(gW0 + (kt) + (size_t)64  * H_DIM, &sW[b][(srow + 64) * BKB + scol_l]); } while (0)

#define STAGE_M(b, kt) do { \
    GLDS(gM0 + (kt),                       &sM[b][(srow     ) * BKB + scol_l]); \
    GLDS(gM0 + (kt) + (size_t)64  * H_DIM, &sM[b][(srow + 64) * BKB + scol_l]); } while (0)

#define BAR()  __builtin_amdgcn_s_barrier()
#define SBAR() __builtin_amdgcn_sched_barrier(0)
#define LGK0() do { asm volatile("s_waitcnt lgkmcnt(0)" ::: "memory"); SBAR(); } while (0)
#define VMC(n) asm volatile("s_waitcnt vmcnt(" #n ")" ::: "memory")

// scale_a = 127 (2^0) for x; scale_b = 123 (2^-4) undoes the *16 pre-scale.
#define MFMASC(a, b, c) \
    __builtin_amdgcn_mfma_scale_f32_16x16x128_f8f6f4(a, b, c, 0, 0, 0, 127, 0, 123)

#define RD_A(dst, buf) do { \
    _Pragma("unroll") for (int m_ = 0; m_ < 4; ++m_) \
        dst[m_] = frag8(sA[buf], arow + m_ * 16, lg); } while (0)
#define RD_B(dst, sb, buf) do { \
    _Pragma("unroll") for (int n_ = 0; n_ < 4; ++n_) \
        dst[n_] = frag8(sb[buf], brw + n_ * 16, lg); } while (0)

#define MM(acc, av, bv) do { \
    _Pragma("unroll") for (int m_ = 0; m_ < 4; ++m_) \
    _Pragma("unroll") for (int n_ = 0; n_ < 4; ++n_) \
        acc[m_][n_] = MFMASC(av[m_], bv[n_], acc[m_][n_]); } while (0)

// PH_W(t): read A(t),W(t); stage A,W,M(t+1)->nt; acc1 += A*W; drain M(t) deps
#define PH_W(ct, nt, kst) do { \
    BAR(); \
    RD_A(aF, ct); RD_B(bW, sW, ct); \
    STAGE_A(nt, kst); STAGE_W(nt, kst); STAGE_M(nt, kst); \
    LGK0(); \
    __builtin_amdgcn_s_setprio(1); MM(acc1, aF, bW); __builtin_amdgcn_s_setprio(0); \
    VMC(8); } while (0)

// PH_M(t): read M(t); acc2 += A*M; drain A,W(t+1)
#define PH_M(ct) do { \
    BAR(); \
    RD_B(bM, sM, ct); \
    LGK0(); \
    __builtin_amdgcn_s_setprio(1); MM(acc2, aF, bM); __builtin_amdgcn_s_setprio(0); \
    VMC(2); } while (0)

// ---- fused dual-GEMM + epilogue ------------------------------------------
__global__ __launch_bounds__(NTHREADS, 2)
void fused_gemm_kernel(const unsigned char* __restrict__ x8,
                       const unsigned char* __restrict__ W8,
                       const unsigned char* __restrict__ M8,
                       const float* __restrict__ x,
                       const float* __restrict__ bias,
                       const float* __restrict__ pm,
                       float* __restrict__ out) {
    __shared__ __align__(16) unsigned char sA[2][BM * BKB];  // 2 x 32 KB
    __shared__ __align__(16) unsigned char sW[2][BN * BKB];  // 2 x 16 KB
    __shared__ __align__(16) unsigned char sM[2][BN * BKB];  // 2 x 16 KB

    const int t    = threadIdx.x;
    const int brow = blockIdx.y * BM;
    const int bcol = blockIdx.x * BN;

    // staging: thread t covers row srow (+64/128/192), 16B chunk (t&7);
    // LDS dest linear, global source chunk pre-swizzled with srow&7.
    const int srow   = t >> 3;
    const int chunk  = t & 7;
    const int scol_l = chunk * 16;
    const int scol_g = (chunk ^ (srow & 7)) * 16;

    const int w    = t >> 6;
    const int lane = t & 63;
    const int wr   = w >> 1;             // 0..3 : 64-row strip
    const int wc   = w & 1;              // 0..1 : 64-col strip
    const int lrow = lane & 15;
    const int lg   = lane >> 4;          // k-group: holds k [32*lg, 32*lg+32)
    const int arow = wr * 64 + lrow;     // A-frag base row (+m*16)
    const int brw  = wc * 64 + lrow;     // B-frag base row (+n*16)

    floatx4 acc1[4][4], acc2[4][4];
#pragma unroll
    for (int m = 0; m < 4; ++m)
#pragma unroll
        for (int n = 0; n < 4; ++n) {
            acc1[m][n] = (floatx4){0.f, 0.f, 0.f, 0.f};
            acc2[m][n] = (floatx4){0.f, 0.f, 0.f, 0.f};
        }

    const unsigned char* gA0 = x8 + (size_t)(brow + srow) * H_DIM + scol_g;
    const unsigned char* gW0 = W8 + (size_t)(bcol + srow) * H_DIM + scol_g;
    const unsigned char* gM0 = M8 + (size_t)(bcol + srow) * H_DIM + scol_g;

    intx8 aF[4], bW[4], bM[4];

    // prologue: stage tile 0 (A:4,W:2,M:2); drain A0,W0 (M0 drains at
    // PH_W(0)'s vmcnt(8)); barrier so ALL waves' stages are visible.
    STAGE_A(0, 0); STAGE_W(0, 0); STAGE_M(0, 0);
    VMC(2);
    BAR();

#pragma unroll 1
    for (int i = 0; i < NKT / 2; ++i) {
        const int ka = ((2 * i + 1) * BKB) & (H_DIM - 1);  // stage for odd tile
        const int kb = ((2 * i + 2) * BKB) & (H_DIM - 1);  // stage for next even
        PH_W(0, 1, ka); PH_M(0);
        PH_W(1, 0, kb); PH_M(1);
    }

    // epilogue: out = xs + sigmoid(S1+b) * xs * S2 * (0.5/H), xs = x*pm (fp32)
    const float c = 0.5f / (float)H_DIM;
#pragma unroll
    for (int n = 0; n < 4; ++n) {
        const int gcol = bcol + wc * 64 + n * 16 + lrow;
        const float bj  = bias[gcol];
        const float pmj = pm[gcol];
#pragma unroll
        for (int m = 0; m < 4; ++m) {
            floatx4 a1 = acc1[m][n];
            floatx4 a2 = acc2[m][n];
            const int growb = brow + wr * 64 + m * 16 + (lane >> 4) * 4;
#pragma unroll
            for (int r = 0; r < 4; ++r) {
                const size_t idx = (size_t)(growb + r) * H_DIM + gcol;
                const float xs  = x[idx] * pmj;
                const float s1  = a1[r] + bj;
                const float sig = 1.0f / (1.0f + __expf(-s1));
                out[idx] = xs + sig * (xs * a2[r] * c);
            }
        }
    }
}

extern "C" void kernel_launch(void* const* d_in, const int* in_sizes, int n_in,
                              void* d_out, int out_size, void* d_ws, size_t ws_size,
                              hipStream_t stream) {
    const float* x   = (const float*)d_in[0];
    const float* W   = (const float*)d_in[1];
    const float* b   = (const float*)d_in[2];
    const float* pm  = (const float*)d_in[3];
    const float* Mk  = (const float*)d_in[4];
    float* out = (float*)d_out;

    const long n_x = (long)M_DIM * H_DIM;      // 33.5M
    const long n_w = (long)H_DIM * H_DIM;      // 4.2M

    // workspace layout (bytes): x8 | W8 | M8  -> ~42 MB total
    unsigned char* x8 = (unsigned char*)d_ws;
    unsigned char* W8 = x8 + n_x;
    unsigned char* M8 = W8 + n_w;

    cvt_x8_kernel<<<2048, 256, 0, stream>>>(x, x8, n_x);
    cvt_wm8_kernel<<<1024, 256, 0, stream>>>(W, Mk, pm, W8, M8, n_w);

    dim3 grid(H_DIM / BN, M_DIM / BM);   // (16, 64)
    fused_gemm_kernel<<<grid, NTHREADS, 0, stream>>>(x8, W8, M8, x, b, pm, out);
}